// Round 1
// baseline (1081.940 us; speedup 1.0000x reference)
//
#include <hip/hip_runtime.h>
#include <hip/hip_bf16.h>

// Problem constants (match reference setup_inputs)
#define Nn 50000
#define Ee 800000
#define Gg 256
#define VOC 120
#define DH 100
#define DFC 32
#define CAPc 25
#define NTYPE 119          // types 1..119
#define NCHUNK 196         // ceil(50000/256)

// ---------------- T = embed @ gcn_w : [120][100] ----------------
__global__ void t_kernel(const float* __restrict__ embed, const float* __restrict__ gcn_w,
                         float* __restrict__ T) {
    int t = blockIdx.x;
    int j = threadIdx.x;
    if (j < DH) {
        float acc = 0.f;
#pragma unroll
        for (int k = 0; k < 32; ++k) acc = fmaf(embed[t * 32 + k], gcn_w[k * DH + j], acc);
        T[t * DH + j] = acc;
    }
}

// ---------------- degrees ----------------
__global__ void deg_kernel(const int* __restrict__ ei, int* __restrict__ outdeg,
                           int* __restrict__ indeg) {
    int e = blockIdx.x * 256 + threadIdx.x;
    if (e < Ee) {
        atomicAdd(&outdeg[ei[e]], 1);
        atomicAdd(&indeg[ei[Ee + e]], 1);
    }
}

// ---------------- W[dst][type] += mask[src]*outdeg[src]^-1/2 ----------------
__global__ void wacc_kernel(const int* __restrict__ ei, const int* __restrict__ feat,
                            const int* __restrict__ outdeg, const float* __restrict__ mask,
                            float* __restrict__ W) {
    int e = blockIdx.x * 256 + threadIdx.x;
    if (e < Ee) {
        int s = ei[e];
        int d = ei[Ee + e];
        float c = rsqrtf((float)max(outdeg[s], 1));
        if (mask) c *= mask[s];
        atomicAdd(&W[d * VOC + feat[s]], c);
    }
}

// ---------------- h = relu((W@T) * indeg^-1/2 + b) : [N][100] ----------------
__global__ __launch_bounds__(128) void h_kernel(const float* __restrict__ W,
                                                const float* __restrict__ T,
                                                const int* __restrict__ indeg,
                                                const float* __restrict__ gcn_b,
                                                float* __restrict__ h) {
    __shared__ float Tl[VOC * DH];  // 48 KB
    for (int idx = threadIdx.x; idx < VOC * DH; idx += 128) Tl[idx] = T[idx];
    __syncthreads();
    int c = threadIdx.x;
    int r0 = blockIdx.x * 32;
    for (int rr = 0; rr < 32; ++rr) {
        int row = r0 + rr;
        if (row >= Nn) break;
        if (c < DH) {
            const float* Wr = W + (size_t)row * VOC;
            float acc = 0.f;
#pragma unroll 12
            for (int t = 0; t < VOC; ++t) acc = fmaf(Wr[t], Tl[t * DH + c], acc);
            float sc = rsqrtf((float)max(indeg[row], 1));
            float v = acc * sc + gcn_b[c];
            h[(size_t)row * DH + c] = v > 0.f ? v : 0.f;
        }
    }
}

// ---------------- pooled[g][j] = max over graph rows (h >= 0, float-bits atomicMax) ----
__global__ void pool_kernel(const float* __restrict__ h, float* __restrict__ pool) {
    int g = blockIdx.x;
    int part = blockIdx.y;           // gridDim.y parts
    int parts = gridDim.y;
    int lo = (g * Nn + Gg - 1) / Gg;
    int hi = ((g + 1) * Nn + Gg - 1) / Gg;
    int j = threadIdx.x;
    if (j >= DH) return;
    float local = 0.f;
    for (int row = lo + part; row < hi; row += parts)
        local = fmaxf(local, h[(size_t)row * DH + j]);
    atomicMax((int*)&pool[g * DH + j], __float_as_int(local));
}

// ---------------- pooled GEMMs + defect prob ----------------
__global__ void poolgemm_kernel(const float* __restrict__ pool, const float* __restrict__ fc_w,
                                const float* __restrict__ fc_b, const float* __restrict__ def_w,
                                const float* __restrict__ def_b, float* __restrict__ out) {
    int g = blockIdx.x;
    __shared__ float xb[32];
    int tid = threadIdx.x;  // 128
    if (tid < 96) {
        int p = tid >> 5, j = tid & 31;
        float acc = fc_b[j];
        const float* pr = pool + p * (Gg * DH) + g * DH;
#pragma unroll 4
        for (int k = 0; k < DH; ++k) acc = fmaf(pr[k], fc_w[k * 32 + j], acc);
        int off = (p == 0) ? 0 : (p == 1 ? 8448 : 16640);
        out[off + g * 32 + j] = acc;
        if (p == 0) xb[j] = acc;
    }
    __syncthreads();
    if (tid < 32) {
        float v = xb[tid] * def_w[tid];
        for (int o = 16; o; o >>= 1) v += __shfl_down(v, o, 64);
        if (tid == 0) out[8192 + g] = 1.f / (1.f + expf(-(v + def_b[0])));
    }
}

// ---------------- selection: first 25 nodes per type, per side ----------------
__global__ void selcount_kernel(const int* __restrict__ feat_src, const int* __restrict__ feat_tar,
                                int* __restrict__ chunkcnt) {
    int chunk = blockIdx.x, side = blockIdx.y;
    const int* f = side ? feat_tar : feat_src;
    __shared__ int hist[VOC];
    int tid = threadIdx.x;
    if (tid < VOC) hist[tid] = 0;
    __syncthreads();
    int i = chunk * 256 + tid;
    if (i < Nn) atomicAdd(&hist[f[i]], 1);
    __syncthreads();
    if (tid < VOC) chunkcnt[(side * NCHUNK + chunk) * VOC + tid] = hist[tid];
}

__global__ void selprefix_kernel(const int* __restrict__ chunkcnt, int* __restrict__ base,
                                 int* __restrict__ fullcnt) {
    int tid = threadIdx.x;  // 256
    if (tid < 2 * VOC) {
        int side = tid / VOC, t = tid % VOC;
        int run = 0;
        for (int c = 0; c < NCHUNK; ++c) {
            base[(side * NCHUNK + c) * VOC + t] = run;
            run += chunkcnt[(side * NCHUNK + c) * VOC + t];
        }
        fullcnt[side * VOC + t] = run;
    }
}

__global__ void selgather_kernel(const int* __restrict__ feat_src, const int* __restrict__ feat_tar,
                                 const int* __restrict__ base, int* __restrict__ selidx) {
    int chunk = blockIdx.x, side = blockIdx.y;
    const int* f = side ? feat_tar : feat_src;
    __shared__ int types[256];
    int tid = threadIdx.x;
    int i = chunk * 256 + tid;
    int t = (i < Nn) ? f[i] : -1;
    types[tid] = t;
    __syncthreads();
    if (t >= 1) {
        int rank = base[(side * NCHUNK + chunk) * VOC + t];
        for (int q = 0; q < tid; ++q) rank += (types[q] == t) ? 1 : 0;
        if (rank < CAPc) selidx[(side * NTYPE + (t - 1)) * CAPc + rank] = i;
    }
}

// ---------------- X features for selected nodes: X[type][50][32] ----------------
__global__ __launch_bounds__(256) void xfeat_kernel(const float* __restrict__ h,
                                                    const int* __restrict__ selidx,
                                                    const int* __restrict__ fullcnt,
                                                    const float* __restrict__ fc_w,
                                                    const float* __restrict__ fc_b,
                                                    float* __restrict__ X, int side) {
    int t = blockIdx.x;  // 0..118 (type t+1)
    __shared__ float fw[DH * 32];
    for (int i = threadIdx.x; i < DH * 32; i += 256) fw[i] = fc_w[i];
    __syncthreads();
    int cnt = min(fullcnt[side * VOC + t + 1], CAPc);
    int j = threadIdx.x & 31, r0 = threadIdx.x >> 5;  // 8 rows in parallel
    for (int r = r0; r < CAPc; r += 8) {
        float acc = 0.f;
        if (r < cnt) {
            int node = selidx[(side * NTYPE + t) * CAPc + r];
            acc = fc_b[j];
            const float* hr = h + (size_t)node * DH;
#pragma unroll 4
            for (int k = 0; k < DH; ++k) acc = fmaf(hr[k], fw[k * 32 + j], acc);
        }
        X[(size_t)t * 1600 + (side * CAPc + r) * 32 + j] = acc;
    }
}

// ---------------- per-type MMD ----------------
__device__ __forceinline__ float block_reduce256(float v, float* red, int tid) {
    __syncthreads();
    red[tid] = v;
    __syncthreads();
    for (int s = 128; s > 0; s >>= 1) {
        if (tid < s) red[tid] += red[tid + s];
        __syncthreads();
    }
    return red[0];
}

__global__ __launch_bounds__(256) void mmd_kernel(const float* __restrict__ X,
                                                  const int* __restrict__ fullcnt,
                                                  float* __restrict__ losses) {
    int t = blockIdx.x;  // type t+1
    __shared__ float Xs[50 * 32];
    __shared__ float D2[50 * 50];
    __shared__ float red[256];
    int tid = threadIdx.x;
    for (int i = tid; i < 1600; i += 256) Xs[i] = X[(size_t)t * 1600 + i];
    __syncthreads();
    int scF = fullcnt[t + 1];
    int tcF = fullcnt[VOC + t + 1];
    int m = min(scF, CAPc), n2 = min(tcF, CAPc);
    float bwpart = 0.f;
    for (int idx = tid; idx < 2500; idx += 256) {
        int i = idx / 50, j = idx % 50;
        float d = 0.f;
#pragma unroll
        for (int k = 0; k < 32; ++k) {
            float df = Xs[i * 32 + k] - Xs[j * 32 + k];
            d = fmaf(df, df, d);
        }
        D2[idx] = d;
        bool vi = (i < CAPc) ? (i < m) : (i - CAPc < n2);
        bool vj = (j < CAPc) ? (j < m) : (j - CAPc < n2);
        if (vi && vj) bwpart += d;
    }
    float bwsum = block_reduce256(bwpart, red, tid);
    float ntot = (float)(m + n2);
    float bw = bwsum / fmaxf(ntot * ntot - ntot, 1.f) * 0.25f;  // / KER_MUL^(KER_NUM//2)
    float bws[5];
#pragma unroll
    for (int k = 0; k < 5; ++k) bws[k] = fmaxf(bw * (float)(1 << k), 1e-8f);
    float xx = 0.f, yy = 0.f, xy = 0.f;
    for (int idx = tid; idx < 2500; idx += 256) {
        int i = idx / 50, j = idx % 50;
        bool vi = (i < CAPc) ? (i < m) : (i - CAPc < n2);
        bool vj = (j < CAPc) ? (j < m) : (j - CAPc < n2);
        if (!(vi && vj)) continue;
        float d = D2[idx];
        float kv = 0.f;
#pragma unroll
        for (int k = 0; k < 5; ++k) kv += expf(-d / bws[k]);
        if (i < CAPc && j < CAPc) xx += kv;
        else if (i >= CAPc && j >= CAPc) yy += kv;
        else if (i < CAPc) xy += kv;
    }
    float rxx = block_reduce256(xx, red, tid);
    float ryy = block_reduce256(yy, red, tid);
    float rxy = block_reduce256(xy, red, tid);
    if (tid == 0) {
        float fm = (float)m, fn = (float)n2;
        float XX = rxx / fmaxf(fm * fm, 1.f);
        float YY = ryy / fmaxf(fn * fn, 1.f);
        float XY = rxy / fmaxf(fm * fn, 1.f);
        float loss = XX + YY - 2.f * XY;
        int inc = (scF >= 5 && tcF >= 5) ? 1 : 0;
        losses[t * 2 + 0] = inc ? loss : 0.f;
        losses[t * 2 + 1] = (float)inc;
    }
}

__global__ void final_kernel(const float* __restrict__ losses, float* __restrict__ out) {
    __shared__ float red[128], redc[128];
    int tid = threadIdx.x;
    float s = 0.f, c = 0.f;
    for (int t = tid; t < NTYPE; t += 128) {
        s += losses[t * 2];
        c += losses[t * 2 + 1];
    }
    red[tid] = s;
    redc[tid] = c;
    __syncthreads();
    for (int st = 64; st > 0; st >>= 1) {
        if (tid < st) {
            red[tid] += red[tid + st];
            redc[tid] += redc[tid + st];
        }
        __syncthreads();
    }
    if (tid == 0) out[24832] = redc[0] > 0.f ? red[0] / fmaxf(redc[0], 1.f) : 0.f;
}

extern "C" void kernel_launch(void* const* d_in, const int* in_sizes, int n_in,
                              void* d_out, int out_size, void* d_ws, size_t ws_size,
                              hipStream_t stream) {
    const int* feat = (const int*)d_in[0];
    const int* feat_src = (const int*)d_in[1];
    const int* feat_tar = (const int*)d_in[2];
    const int* ei0 = (const int*)d_in[3];
    const int* ei1 = (const int*)d_in[4];
    const int* ei2 = (const int*)d_in[5];
    const float* mask = (const float*)d_in[7];
    const float* embed = (const float*)d_in[8];
    const float* gcn_w = (const float*)d_in[9];
    const float* gcn_b = (const float*)d_in[10];
    const float* fc_w = (const float*)d_in[11];
    const float* fc_b = (const float*)d_in[12];
    const float* def_w = (const float*)d_in[13];
    const float* def_b = (const float*)d_in[14];
    float* out = (float*)d_out;

    char* wsb = (char*)d_ws;
    float* W = (float*)(wsb + 0);              // 24,000,000
    float* h = (float*)(wsb + 24000000);       // 20,000,000
    float* T = (float*)(wsb + 44000000);       // 48,000
    int* outdeg = (int*)(wsb + 44048000);      // 200,000
    int* indeg = (int*)(wsb + 44248000);       // 200,000
    float* pool = (float*)(wsb + 44448000);    // 307,200
    int* chunkcnt = (int*)(wsb + 44755200);    // 188,160
    int* baseb = (int*)(wsb + 44943360);       // 188,160
    int* selidx = (int*)(wsb + 45131520);      // 23,800
    int* fullcnt = (int*)(wsb + 45155320);     // 960
    float* X = (float*)(wsb + 45156280);       // 761,600
    float* losses = (float*)(wsb + 45917880);  // 952

    const int* feats[3] = {feat, feat_src, feat_tar};
    const int* eis[3] = {ei0, ei1, ei2};
    const float* masks[3] = {mask, nullptr, nullptr};

    hipMemsetAsync(pool, 0, 3 * Gg * DH * sizeof(float), stream);

    t_kernel<<<VOC, 128, 0, stream>>>(embed, gcn_w, T);

    // node-type selection (independent of h)
    selcount_kernel<<<dim3(NCHUNK, 2), 256, 0, stream>>>(feat_src, feat_tar, chunkcnt);
    selprefix_kernel<<<1, 256, 0, stream>>>(chunkcnt, baseb, fullcnt);
    selgather_kernel<<<dim3(NCHUNK, 2), 256, 0, stream>>>(feat_src, feat_tar, baseb, selidx);

    for (int p = 0; p < 3; ++p) {
        hipMemsetAsync(outdeg, 0, Nn * sizeof(int), stream);
        hipMemsetAsync(indeg, 0, Nn * sizeof(int), stream);
        hipMemsetAsync(W, 0, (size_t)Nn * VOC * sizeof(float), stream);
        deg_kernel<<<(Ee + 255) / 256, 256, 0, stream>>>(eis[p], outdeg, indeg);
        wacc_kernel<<<(Ee + 255) / 256, 256, 0, stream>>>(eis[p], feats[p], outdeg, masks[p], W);
        h_kernel<<<(Nn + 31) / 32, 128, 0, stream>>>(W, T, indeg, gcn_b, h);
        pool_kernel<<<dim3(Gg, 8), 128, 0, stream>>>(h, pool + p * (Gg * DH));
        if (p == 1) xfeat_kernel<<<NTYPE, 256, 0, stream>>>(h, selidx, fullcnt, fc_w, fc_b, X, 0);
        if (p == 2) xfeat_kernel<<<NTYPE, 256, 0, stream>>>(h, selidx, fullcnt, fc_w, fc_b, X, 1);
    }

    poolgemm_kernel<<<Gg, 128, 0, stream>>>(pool, fc_w, fc_b, def_w, def_b, out);
    mmd_kernel<<<NTYPE, 256, 0, stream>>>(X, fullcnt, losses);
    final_kernel<<<1, 128, 0, stream>>>(losses, out);
}

// Round 2
// 576.638 us; speedup vs baseline: 1.8763x; 1.8763x over previous
//
#include <hip/hip_runtime.h>
#include <hip/hip_bf16.h>

// Problem constants (match reference setup_inputs)
#define Nn 50000
#define Ee 800000
#define Gg 256
#define VOC 120
#define DH 100
#define DFC 32
#define CAPc 25
#define NTYPE 119          // types 1..119
#define NCHUNK 196         // ceil(50000/256)

// ---------------- T = embed @ gcn_w : [120][100] ----------------
__global__ void t_kernel(const float* __restrict__ embed, const float* __restrict__ gcn_w,
                         float* __restrict__ T) {
    int t = blockIdx.x;
    int j = threadIdx.x;
    if (j < DH) {
        float acc = 0.f;
#pragma unroll
        for (int k = 0; k < 32; ++k) acc = fmaf(embed[t * 32 + k], gcn_w[k * DH + j], acc);
        T[t * DH + j] = acc;
    }
}

// ---------------- degrees ----------------
__global__ void deg_kernel(const int* __restrict__ ei, int* __restrict__ outdeg,
                           int* __restrict__ indeg) {
    int e = blockIdx.x * 256 + threadIdx.x;
    if (e < Ee) {
        atomicAdd(&outdeg[ei[e]], 1);
        atomicAdd(&indeg[ei[Ee + e]], 1);
    }
}

// ---------------- W[dst][type] += mask[src]*outdeg[src]^-1/2 ----------------
__global__ void wacc_kernel(const int* __restrict__ ei, const int* __restrict__ feat,
                            const int* __restrict__ outdeg, const float* __restrict__ mask,
                            float* __restrict__ W) {
    int e = blockIdx.x * 256 + threadIdx.x;
    if (e < Ee) {
        int s = ei[e];
        int d = ei[Ee + e];
        float c = rsqrtf((float)max(outdeg[s], 1));
        if (mask) c *= mask[s];
        atomicAdd(&W[d * VOC + feat[s]], c);
    }
}

// ---------------- h = relu((W@T) * indeg^-1/2 + b) : [N][100] ----------------
// 256 threads, 64 rows/block. Register tile: 8 rows x 4 cols per thread.
// LDS: T (48000 B) + W tile (30720 B) = 78720 B -> 2 blocks/CU.
__global__ __launch_bounds__(256, 2) void h_kernel(const float* __restrict__ W,
                                                   const float* __restrict__ T,
                                                   const int* __restrict__ indeg,
                                                   const float* __restrict__ gcn_b,
                                                   float* __restrict__ h) {
    __shared__ float smem[12000 + 64 * 120];
    float* Tl = smem;
    float* Wt = smem + 12000;
    int tid = threadIdx.x;
    int r0 = blockIdx.x * 64;

    float4* Tl4 = (float4*)Tl;
    const float4* Tg4 = (const float4*)T;
#pragma unroll
    for (int i = 0; i < 12; ++i) {
        int idx = tid + i * 256;
        if (idx < 3000) Tl4[idx] = Tg4[idx];
    }
    float4* Wt4 = (float4*)Wt;
    const float4* Wg4 = (const float4*)(W + (size_t)r0 * VOC);
#pragma unroll
    for (int i = 0; i < 8; ++i) {
        int idx = tid + i * 256;
        if (idx < 1920) Wt4[idx] = Wg4[idx];  // last block over-reads into ws (harmless)
    }
    __syncthreads();

    int tc = tid & 31, tr = tid >> 5;
    int c0 = tc * 4;
    float4 acc[8];
#pragma unroll
    for (int u = 0; u < 8; ++u) acc[u] = make_float4(0.f, 0.f, 0.f, 0.f);

#pragma unroll 2
    for (int tq = 0; tq < 30; ++tq) {
        const float* tb = &Tl[tq * 4 * DH + c0];
        float4 tv0 = *(const float4*)(tb);
        float4 tv1 = *(const float4*)(tb + DH);
        float4 tv2 = *(const float4*)(tb + 2 * DH);
        float4 tv3 = *(const float4*)(tb + 3 * DH);
#pragma unroll
        for (int u = 0; u < 8; ++u) {
            float4 wv = *(const float4*)&Wt[(tr * 8 + u) * VOC + tq * 4];
            acc[u].x = fmaf(wv.x, tv0.x, fmaf(wv.y, tv1.x, fmaf(wv.z, tv2.x, fmaf(wv.w, tv3.x, acc[u].x))));
            acc[u].y = fmaf(wv.x, tv0.y, fmaf(wv.y, tv1.y, fmaf(wv.z, tv2.y, fmaf(wv.w, tv3.y, acc[u].y))));
            acc[u].z = fmaf(wv.x, tv0.z, fmaf(wv.y, tv1.z, fmaf(wv.z, tv2.z, fmaf(wv.w, tv3.z, acc[u].z))));
            acc[u].w = fmaf(wv.x, tv0.w, fmaf(wv.y, tv1.w, fmaf(wv.z, tv2.w, fmaf(wv.w, tv3.w, acc[u].w))));
        }
    }

    if (tc < 25) {
        float4 bias = *(const float4*)&gcn_b[c0];
#pragma unroll
        for (int u = 0; u < 8; ++u) {
            int row = r0 + tr * 8 + u;
            if (row < Nn) {
                float sc = rsqrtf((float)max(indeg[row], 1));
                float4 v;
                v.x = fmaxf(acc[u].x * sc + bias.x, 0.f);
                v.y = fmaxf(acc[u].y * sc + bias.y, 0.f);
                v.z = fmaxf(acc[u].z * sc + bias.z, 0.f);
                v.w = fmaxf(acc[u].w * sc + bias.w, 0.f);
                *(float4*)&h[(size_t)row * DH + c0] = v;
            }
        }
    }
}

// ---------------- pooled[g][:] = max over graph rows (h >= 0) ----------------
// one block per graph; float4 coalesced reads; LDS tree reduce; no atomics.
__global__ __launch_bounds__(256) void pool_kernel(const float* __restrict__ h,
                                                   float* __restrict__ pool) {
    int g = blockIdx.x;
    int lo = (g * Nn + Gg - 1) / Gg;
    int hi = ((g + 1) * Nn + Gg - 1) / Gg;
    int tid = threadIdx.x;
    int q = tid & 31, rg = tid >> 5;  // q: col-quad (q<25 active), rg: 8 row groups
    const float4* h4 = (const float4*)h;
    float4 mx = make_float4(0.f, 0.f, 0.f, 0.f);
    if (q < 25) {
        for (int r = lo + rg; r < hi; r += 8) {
            float4 v = h4[(size_t)r * 25 + q];
            mx.x = fmaxf(mx.x, v.x);
            mx.y = fmaxf(mx.y, v.y);
            mx.z = fmaxf(mx.z, v.z);
            mx.w = fmaxf(mx.w, v.w);
        }
    }
    __shared__ float4 sm[256];
    sm[tid] = mx;
    __syncthreads();
#pragma unroll
    for (int s = 4; s > 0; s >>= 1) {
        if (rg < s) {
            float4 o = sm[tid + s * 32];
            float4 m = sm[tid];
            m.x = fmaxf(m.x, o.x);
            m.y = fmaxf(m.y, o.y);
            m.z = fmaxf(m.z, o.z);
            m.w = fmaxf(m.w, o.w);
            sm[tid] = m;
        }
        __syncthreads();
    }
    if (rg == 0 && q < 25) *(float4*)&pool[g * DH + q * 4] = sm[tid];
}

// ---------------- pooled GEMMs + defect prob ----------------
__global__ void poolgemm_kernel(const float* __restrict__ pool, const float* __restrict__ fc_w,
                                const float* __restrict__ fc_b, const float* __restrict__ def_w,
                                const float* __restrict__ def_b, float* __restrict__ out) {
    int g = blockIdx.x;
    __shared__ float xb[32];
    int tid = threadIdx.x;  // 128
    if (tid < 96) {
        int p = tid >> 5, j = tid & 31;
        float acc = fc_b[j];
        const float* pr = pool + p * (Gg * DH) + g * DH;
#pragma unroll 4
        for (int k = 0; k < DH; ++k) acc = fmaf(pr[k], fc_w[k * 32 + j], acc);
        int off = (p == 0) ? 0 : (p == 1 ? 8448 : 16640);
        out[off + g * 32 + j] = acc;
        if (p == 0) xb[j] = acc;
    }
    __syncthreads();
    if (tid < 32) {
        float v = xb[tid] * def_w[tid];
        for (int o = 16; o; o >>= 1) v += __shfl_down(v, o, 64);
        if (tid == 0) out[8192 + g] = 1.f / (1.f + expf(-(v + def_b[0])));
    }
}

// ---------------- selection: first 25 nodes per type, per side ----------------
__global__ void selcount_kernel(const int* __restrict__ feat_src, const int* __restrict__ feat_tar,
                                int* __restrict__ chunkcnt) {
    int chunk = blockIdx.x, side = blockIdx.y;
    const int* f = side ? feat_tar : feat_src;
    __shared__ int hist[VOC];
    int tid = threadIdx.x;
    if (tid < VOC) hist[tid] = 0;
    __syncthreads();
    int i = chunk * 256 + tid;
    if (i < Nn) atomicAdd(&hist[f[i]], 1);
    __syncthreads();
    if (tid < VOC) chunkcnt[(side * NCHUNK + chunk) * VOC + tid] = hist[tid];
}

__global__ void selprefix_kernel(const int* __restrict__ chunkcnt, int* __restrict__ base,
                                 int* __restrict__ fullcnt) {
    int tid = threadIdx.x;  // 256
    if (tid < 2 * VOC) {
        int side = tid / VOC, t = tid % VOC;
        int run = 0;
        for (int c = 0; c < NCHUNK; ++c) {
            base[(side * NCHUNK + c) * VOC + t] = run;
            run += chunkcnt[(side * NCHUNK + c) * VOC + t];
        }
        fullcnt[side * VOC + t] = run;
    }
}

__global__ void selgather_kernel(const int* __restrict__ feat_src, const int* __restrict__ feat_tar,
                                 const int* __restrict__ base, int* __restrict__ selidx) {
    int chunk = blockIdx.x, side = blockIdx.y;
    const int* f = side ? feat_tar : feat_src;
    __shared__ int types[256];
    int tid = threadIdx.x;
    int i = chunk * 256 + tid;
    int t = (i < Nn) ? f[i] : -1;
    types[tid] = t;
    int bv = 0;
    bool need = (t >= 1);
    if (need) {
        bv = base[(side * NCHUNK + chunk) * VOC + t];
        need = (bv < CAPc);
    }
    int any = __syncthreads_count((int)need);  // also the barrier making types[] visible
    if (any == 0) return;                      // ~97% of blocks exit here
    if (need) {
        int rank = bv;
        for (int q = 0; q < 256; ++q)
            if (q < tid && types[q] == t) rank++;
        if (rank < CAPc) selidx[(side * NTYPE + (t - 1)) * CAPc + rank] = i;
    }
}

// ---------------- X features for selected nodes: X[type][50][32] ----------------
__global__ __launch_bounds__(256) void xfeat_kernel(const float* __restrict__ h,
                                                    const int* __restrict__ selidx,
                                                    const int* __restrict__ fullcnt,
                                                    const float* __restrict__ fc_w,
                                                    const float* __restrict__ fc_b,
                                                    float* __restrict__ X, int side) {
    int t = blockIdx.x;  // 0..118 (type t+1)
    __shared__ float fw[DH * 32];
    for (int i = threadIdx.x; i < DH * 32; i += 256) fw[i] = fc_w[i];
    __syncthreads();
    int cnt = min(fullcnt[side * VOC + t + 1], CAPc);
    int j = threadIdx.x & 31, r0 = threadIdx.x >> 5;  // 8 rows in parallel
    for (int r = r0; r < CAPc; r += 8) {
        float acc = 0.f;
        if (r < cnt) {
            int node = selidx[(side * NTYPE + t) * CAPc + r];
            acc = fc_b[j];
            const float* hr = h + (size_t)node * DH;
#pragma unroll 4
            for (int k = 0; k < DH; ++k) acc = fmaf(hr[k], fw[k * 32 + j], acc);
        }
        X[(size_t)t * 1600 + (side * CAPc + r) * 32 + j] = acc;
    }
}

// ---------------- per-type MMD ----------------
__device__ __forceinline__ float block_reduce256(float v, float* red, int tid) {
    __syncthreads();
    red[tid] = v;
    __syncthreads();
    for (int s = 128; s > 0; s >>= 1) {
        if (tid < s) red[tid] += red[tid + s];
        __syncthreads();
    }
    return red[0];
}

__global__ __launch_bounds__(256) void mmd_kernel(const float* __restrict__ X,
                                                  const int* __restrict__ fullcnt,
                                                  float* __restrict__ losses) {
    int t = blockIdx.x;  // type t+1
    __shared__ float Xs[50 * 32];
    __shared__ float D2[50 * 50];
    __shared__ float red[256];
    int tid = threadIdx.x;
    for (int i = tid; i < 1600; i += 256) Xs[i] = X[(size_t)t * 1600 + i];
    __syncthreads();
    int scF = fullcnt[t + 1];
    int tcF = fullcnt[VOC + t + 1];
    int m = min(scF, CAPc), n2 = min(tcF, CAPc);
    float bwpart = 0.f;
    for (int idx = tid; idx < 2500; idx += 256) {
        int i = idx / 50, j = idx % 50;
        float d = 0.f;
#pragma unroll
        for (int k = 0; k < 32; ++k) {
            float df = Xs[i * 32 + k] - Xs[j * 32 + k];
            d = fmaf(df, df, d);
        }
        D2[idx] = d;
        bool vi = (i < CAPc) ? (i < m) : (i - CAPc < n2);
        bool vj = (j < CAPc) ? (j < m) : (j - CAPc < n2);
        if (vi && vj) bwpart += d;
    }
    float bwsum = block_reduce256(bwpart, red, tid);
    float ntot = (float)(m + n2);
    float bw = bwsum / fmaxf(ntot * ntot - ntot, 1.f) * 0.25f;  // / KER_MUL^(KER_NUM//2)
    float bws[5];
#pragma unroll
    for (int k = 0; k < 5; ++k) bws[k] = fmaxf(bw * (float)(1 << k), 1e-8f);
    float xx = 0.f, yy = 0.f, xy = 0.f;
    for (int idx = tid; idx < 2500; idx += 256) {
        int i = idx / 50, j = idx % 50;
        bool vi = (i < CAPc) ? (i < m) : (i - CAPc < n2);
        bool vj = (j < CAPc) ? (j < m) : (j - CAPc < n2);
        if (!(vi && vj)) continue;
        float d = D2[idx];
        float kv = 0.f;
#pragma unroll
        for (int k = 0; k < 5; ++k) kv += expf(-d / bws[k]);
        if (i < CAPc && j < CAPc) xx += kv;
        else if (i >= CAPc && j >= CAPc) yy += kv;
        else if (i < CAPc) xy += kv;
    }
    float rxx = block_reduce256(xx, red, tid);
    float ryy = block_reduce256(yy, red, tid);
    float rxy = block_reduce256(xy, red, tid);
    if (tid == 0) {
        float fm = (float)m, fn = (float)n2;
        float XX = rxx / fmaxf(fm * fm, 1.f);
        float YY = ryy / fmaxf(fn * fn, 1.f);
        float XY = rxy / fmaxf(fm * fn, 1.f);
        float loss = XX + YY - 2.f * XY;
        int inc = (scF >= 5 && tcF >= 5) ? 1 : 0;
        losses[t * 2 + 0] = inc ? loss : 0.f;
        losses[t * 2 + 1] = (float)inc;
    }
}

__global__ void final_kernel(const float* __restrict__ losses, float* __restrict__ out) {
    __shared__ float red[128], redc[128];
    int tid = threadIdx.x;
    float s = 0.f, c = 0.f;
    for (int t = tid; t < NTYPE; t += 128) {
        s += losses[t * 2];
        c += losses[t * 2 + 1];
    }
    red[tid] = s;
    redc[tid] = c;
    __syncthreads();
    for (int st = 64; st > 0; st >>= 1) {
        if (tid < st) {
            red[tid] += red[tid + st];
            redc[tid] += redc[tid + st];
        }
        __syncthreads();
    }
    if (tid == 0) out[24832] = redc[0] > 0.f ? red[0] / fmaxf(redc[0], 1.f) : 0.f;
}

extern "C" void kernel_launch(void* const* d_in, const int* in_sizes, int n_in,
                              void* d_out, int out_size, void* d_ws, size_t ws_size,
                              hipStream_t stream) {
    const int* feat = (const int*)d_in[0];
    const int* feat_src = (const int*)d_in[1];
    const int* feat_tar = (const int*)d_in[2];
    const int* ei0 = (const int*)d_in[3];
    const int* ei1 = (const int*)d_in[4];
    const int* ei2 = (const int*)d_in[5];
    const float* mask = (const float*)d_in[7];
    const float* embed = (const float*)d_in[8];
    const float* gcn_w = (const float*)d_in[9];
    const float* gcn_b = (const float*)d_in[10];
    const float* fc_w = (const float*)d_in[11];
    const float* fc_b = (const float*)d_in[12];
    const float* def_w = (const float*)d_in[13];
    const float* def_b = (const float*)d_in[14];
    float* out = (float*)d_out;

    char* wsb = (char*)d_ws;
    float* W = (float*)(wsb + 0);              // 24,000,000
    float* h = (float*)(wsb + 24000000);       // 20,000,000
    float* T = (float*)(wsb + 44000000);       // 48,000
    int* outdeg = (int*)(wsb + 44048000);      // 200,000
    int* indeg = (int*)(wsb + 44248000);       // 200,000 (adjacent to outdeg)
    float* pool = (float*)(wsb + 44448000);    // 307,200
    int* chunkcnt = (int*)(wsb + 44755200);    // 188,160
    int* baseb = (int*)(wsb + 44943360);       // 188,160
    int* selidx = (int*)(wsb + 45131520);      // 23,800
    int* fullcnt = (int*)(wsb + 45155320);     // 960
    float* X = (float*)(wsb + 45156280);       // 761,600
    float* losses = (float*)(wsb + 45917880);  // 952

    const int* feats[3] = {feat, feat_src, feat_tar};
    const int* eis[3] = {ei0, ei1, ei2};
    const float* masks[3] = {mask, nullptr, nullptr};

    t_kernel<<<VOC, 128, 0, stream>>>(embed, gcn_w, T);

    // node-type selection (independent of h)
    selcount_kernel<<<dim3(NCHUNK, 2), 256, 0, stream>>>(feat_src, feat_tar, chunkcnt);
    selprefix_kernel<<<1, 256, 0, stream>>>(chunkcnt, baseb, fullcnt);
    selgather_kernel<<<dim3(NCHUNK, 2), 256, 0, stream>>>(feat_src, feat_tar, baseb, selidx);

    for (int p = 0; p < 3; ++p) {
        hipMemsetAsync(outdeg, 0, 2 * Nn * sizeof(int), stream);  // outdeg + indeg
        hipMemsetAsync(W, 0, (size_t)Nn * VOC * sizeof(float), stream);
        deg_kernel<<<(Ee + 255) / 256, 256, 0, stream>>>(eis[p], outdeg, indeg);
        wacc_kernel<<<(Ee + 255) / 256, 256, 0, stream>>>(eis[p], feats[p], outdeg, masks[p], W);
        h_kernel<<<(Nn + 63) / 64, 256, 0, stream>>>(W, T, indeg, gcn_b, h);
        pool_kernel<<<Gg, 256, 0, stream>>>(h, pool + p * (Gg * DH));
        if (p == 1) xfeat_kernel<<<NTYPE, 256, 0, stream>>>(h, selidx, fullcnt, fc_w, fc_b, X, 0);
        if (p == 2) xfeat_kernel<<<NTYPE, 256, 0, stream>>>(h, selidx, fullcnt, fc_w, fc_b, X, 1);
    }

    poolgemm_kernel<<<Gg, 128, 0, stream>>>(pool, fc_w, fc_b, def_w, def_b, out);
    mmd_kernel<<<NTYPE, 256, 0, stream>>>(X, fullcnt, losses);
    final_kernel<<<1, 128, 0, stream>>>(losses, out);
}